// Round 13
// baseline (499.529 us; speedup 1.0000x reference)
//
#include <hip/hip_runtime.h>

#define DT_F 0.01f
#define EPS_F 1e-5f
#define NEG_INF_I (-1073741824)
#define NEC 1024   // padded event capacity (stride of evtabT rows)

typedef _Float16 f16;
typedef _Float16 f16x2 __attribute__((ext_vector_type(2)));
typedef _Float16 f16x8 __attribute__((ext_vector_type(8)));
typedef float f32x4 __attribute__((ext_vector_type(4)));

#define MFMA16(a, b, c) __builtin_amdgcn_mfma_f32_16x16x32_f16((a), (b), (c), 0, 0, 0)

__device__ __forceinline__ float rl(float v, int l) {
  return __int_as_float(__builtin_amdgcn_readlane(__float_as_int(v), l));
}
__device__ __forceinline__ float sigm(float x) {
  float e = __builtin_amdgcn_exp2f(-1.442695041f * x);
  return __builtin_amdgcn_rcpf(1.0f + e);
}
__device__ __forceinline__ float tanhf_fast(float x) {
  float e = __builtin_amdgcn_exp2f(2.885390082f * x);
  return fmaf(-2.0f, __builtin_amdgcn_rcpf(e + 1.0f), 1.0f);
}
__device__ __forceinline__ float dot2(unsigned w, unsigned h, float acc) {
  return __builtin_amdgcn_fdot2(__builtin_bit_cast(f16x2, w),
                                __builtin_bit_cast(f16x2, h), acc, false);
}
__device__ __forceinline__ unsigned packf16(float a, float b) {
  return __builtin_bit_cast(unsigned, __builtin_amdgcn_cvt_pkrtz(a, b));
}
#define ANCH4(v) asm volatile("" : "+v"((v).x), "+v"((v).y), "+v"((v).z), "+v"((v).w))

// In-register wave broadcast of packed f16 pairs:
// pair_p = (val[2p], val[2p+1]) replicated to all lanes via readlane -> SGPRs.
#define BCAST(dst, val)                                                    \
  {                                                                        \
    float _hn = __shfl_xor((val), 1);                                      \
    float _a = (lane & 1) ? _hn : (val);                                   \
    float _b = (lane & 1) ? (val) : _hn;                                   \
    unsigned _pr = packf16(_a, _b);                                        \
    _Pragma("unroll")                                                      \
    for (int _p = 0; _p < 32; ++_p)                                        \
      (dst)[_p] = (unsigned)__builtin_amdgcn_readlane((int)_pr, 2 * _p);   \
  }

// evtabT[sid*NEC + k] = (last obs index in event k's window with sample_ids==sid)+1, or 0.
__global__ void build_evtab_kernel(const int* __restrict__ sample_ids,
                                   const int* __restrict__ time_ptr,
                                   int* __restrict__ evtabT, int B, int ope) {
  int k = blockIdx.x;
  int base = time_ptr[k];
  for (int t = threadIdx.x; t < ope; t += blockDim.x) {
    int obs = base + t;
    int sid = sample_ids[obs];
    atomicMax(&evtabT[(long)sid * NEC + k], obs + 1);   // last occurrence wins
  }
}

// f16-pair packing (verified R7)
__global__ void pack_pairs_kernel(const float* __restrict__ ghr,
                                  const float* __restrict__ ghz,
                                  const float* __restrict__ ghh,
                                  const float* __restrict__ gbWhh,
                                  const float* __restrict__ gbWih,
                                  unsigned* __restrict__ odeP,
                                  unsigned* __restrict__ bayP,
                                  unsigned* __restrict__ wihP, int IN) {
  int idx = blockIdx.x * 256 + threadIdx.x;
  if (idx < 3 * 64 * 32) {
    int p = idx & 31, r = idx >> 5;
    int g = r >> 6, i = r & 63;
    const float* src = (g == 0) ? ghr : ((g == 1) ? ghz : ghh);
    odeP[idx] = packf16(src[i * 64 + 2 * p], src[i * 64 + 2 * p + 1]);
    bayP[idx] = packf16(gbWhh[r * 64 + 2 * p], gbWhh[r * 64 + 2 * p + 1]);
  }
  if (idx < 3 * 64 * 4) {
    int p = idx & 3, r = idx >> 2;
    float a = (2 * p < IN) ? gbWih[r * IN + 2 * p] : 0.0f;
    float b = (2 * p + 1 < IN) ? gbWih[r * IN + 2 * p + 1] : 0.0f;
    wihP[idx] = packf16(a, b);
  }
}

// W1 -> MFMA B-fragments (layout HW-verified in R5)
__global__ void pack_head_kernel(const float* __restrict__ W1, f16* __restrict__ w1P) {
  int f = blockIdx.x;       // 0..15
  int l = threadIdx.x;      // 0..63
  int t = f >> 1, kf = f & 1;
  int n = 16 * t + (l & 15);
  for (int j = 0; j < 8; ++j) {
    int k = 8 * (l >> 4) + j + 32 * kf;
    w1P[f * 512 + l * 8 + j] = (f16)W1[n * 64 + k];
  }
}

// One wave per sample, 4 waves/block, 256 blocks. ZERO barriers and ZERO LDS
// in the steady-state loop: h / r*h broadcasts live in SGPRs (readlane pairs).
__global__ __launch_bounds__(256, 1) void evolve_kernel(
    const float* __restrict__ time_uniq,
    const float* __restrict__ X,
    const float* __restrict__ covs,
    const float* __restrict__ cov_W1, const float* __restrict__ cov_b1,
    const float* __restrict__ cov_W2, const float* __restrict__ cov_b2,
    const float* __restrict__ gb_bih, const float* __restrict__ gb_bhh,
    const float* __restrict__ gx_b,
    const unsigned* __restrict__ odeP, const unsigned* __restrict__ bayP,
    const unsigned* __restrict__ wihP,
    const int* __restrict__ evtabT,
    f16* __restrict__ hp16,
    int B, int NE, int n_steps, int IN, int COV)
{
  __shared__ unsigned sBW[3 * 64 * 32];          // Bayes pairs, swizzled (24KB; event steps only)
  __shared__ int sStep[1024];                    // event -> grid step (4KB)

  const int tid = threadIdx.x;
  const int wid = tid >> 6, lane = tid & 63;
  const int b = blockIdx.x * 4 + wid;
  const bool alive = (b < B);
  const int necap = (NE < NEC) ? NE : NEC;

  for (int idx = tid; idx < 3 * 64 * 32; idx += 256) {
    int c = idx & 31, r = idx >> 5;
    int i = r & 63, s = c >> 2;
    sBW[r * 32 + (((s ^ (i & 7)) << 2) | (c & 3))] = bayP[idx];
  }
  if (wid == 0) {     // wave-parallel prefix-max event schedule (verified R6/R7)
    int pm = NEG_INF_I;
    int loc[16];
#pragma unroll
    for (int j = 0; j < 16; ++j) {
      int e = lane * 16 + j;
      int gv = NEG_INF_I;
      if (e < necap) {
        float tu = time_uniq[e];
        int k0 = (int)floorf((tu - EPS_F) * 100.0f) - 2;
        if (k0 < 0) k0 = 0;
        while ((float)k0 * DT_F + EPS_F < tu) ++k0;
        gv = k0 - e;
      }
      pm = max(pm, gv);
      loc[j] = pm;
    }
    int tot = pm;
#pragma unroll
    for (int off = 1; off < 64; off <<= 1) {
      int v = __shfl_up(tot, off);
      if (lane >= off) tot = max(tot, v);
    }
    int excl = __shfl_up(tot, 1);
    if (lane == 0) excl = NEG_INF_I;
#pragma unroll
    for (int j = 0; j < 16; ++j)
      sStep[lane * 16 + j] = lane * 16 + j + max(loc[j], excl);
  }
  __syncthreads();   // init only

  // ---- ODE weights: load once, anchor once ----
  const uint4* odeQ = (const uint4*)odeP;
  uint4 WR[8], WZ[8], WU[8];
#pragma unroll
  for (int q = 0; q < 8; ++q) {
    WR[q] = odeQ[(0 * 64 + lane) * 8 + q];
    WZ[q] = odeQ[(1 * 64 + lane) * 8 + q];
    WU[q] = odeQ[(2 * 64 + lane) * 8 + q];
  }
#pragma unroll
  for (int q = 0; q < 8; ++q) { ANCH4(WR[q]); ANCH4(WZ[q]); ANCH4(WU[q]); }
  const uint4* wihQ = (const uint4*)wihP;

  const float xr = gx_b[lane], xz = gx_b[64 + lane], xh = gx_b[128 + lane];
  const float crz_r = gb_bih[lane] + gb_bhh[lane];
  const float crz_z = gb_bih[64 + lane] + gb_bhh[64 + lane];
  const float bihn = gb_bih[128 + lane], bhhn = gb_bhh[128 + lane];

  // ---- h0 ----
  float h = 0.0f;
  if (alive) {
    float cacc = cov_b1[lane];
    for (int c = 0; c < COV; ++c)
      cacc = fmaf(covs[b * COV + c], cov_W1[lane * COV + c], cacc);
    float cl = fmaxf(cacc, 0.0f);
    float hacc = cov_b2[lane];
#pragma unroll
    for (int j = 0; j < 64; ++j)
      hacc = fmaf(rl(cl, j), cov_W2[lane * 64 + j], hacc);
    h = tanhf_fast(hacc);
  }

  unsigned hp[32];
  BCAST(hp, h);                                  // invariant: hp == pairs(h)

  // ---- event pipeline (2-deep; evtabT row is contiguous & uniform per wave) ----
  const int* evrow = evtabT + (long)b * NEC;
  int e_next = 0, s_next = 0x7fffffff, v_cur = 0, v_pipe = 0;
  float xf[8];
#pragma unroll
  for (int kk = 0; kk < 8; ++kk) xf[kk] = 0.0f;
  if (necap > 0) {
    s_next = sStep[0];
    if (alive) {
      v_cur = evrow[0];
      if (v_cur > 0) {
        const float* xp = X + (long)(v_cur - 1) * IN;
#pragma unroll
        for (int kk = 0; kk < 8; ++kk) xf[kk] = (kk < IN) ? xp[kk] : 0.0f;
      }
      v_pipe = (necap > 1) ? evrow[1] : 0;
    }
  }

  f16* hps = hp16 + (long)b * 64 + lane;
  const long rowstride = (long)B * 64;

#pragma unroll 1
  for (int k = 0; k < n_steps; ++k) {
    if (k == s_next) {                       // wave-uniform schedule
      if (v_cur > 0) {                       // this sample fires
        unsigned xp0 = packf16(xf[0], xf[1]), xp1 = packf16(xf[2], xf[3]);
        unsigned xp2 = packf16(xf[4], xf[5]), xp3 = packf16(xf[6], xf[7]);
        uint4 wxr = wihQ[lane], wxz = wihQ[64 + lane], wxn = wihQ[128 + lane];
        float ar = crz_r, az = crz_z, anh = bhhn, ani = bihn;
        ar = dot2(wxr.x, xp0, ar); ar = dot2(wxr.y, xp1, ar);
        ar = dot2(wxr.z, xp2, ar); ar = dot2(wxr.w, xp3, ar);
        az = dot2(wxz.x, xp0, az); az = dot2(wxz.y, xp1, az);
        az = dot2(wxz.z, xp2, az); az = dot2(wxz.w, xp3, az);
        ani = dot2(wxn.x, xp0, ani); ani = dot2(wxn.y, xp1, ani);
        ani = dot2(wxn.z, xp2, ani); ani = dot2(wxn.w, xp3, ani);
        float ar1 = 0.f, az1 = 0.f, an1 = 0.f;
#pragma unroll
        for (int q = 0; q < 8; ++q) {
          int sw = ((q ^ (lane & 7)) << 2);
          uint4 br = *(const uint4*)&sBW[(0 * 64 + lane) * 32 + sw];
          uint4 bz = *(const uint4*)&sBW[(1 * 64 + lane) * 32 + sw];
          uint4 bn = *(const uint4*)&sBW[(2 * 64 + lane) * 32 + sw];
          ar  = dot2(br.x, hp[4 * q + 0], ar);   ar1 = dot2(br.y, hp[4 * q + 1], ar1);
          ar  = dot2(br.z, hp[4 * q + 2], ar);   ar1 = dot2(br.w, hp[4 * q + 3], ar1);
          az  = dot2(bz.x, hp[4 * q + 0], az);   az1 = dot2(bz.y, hp[4 * q + 1], az1);
          az  = dot2(bz.z, hp[4 * q + 2], az);   az1 = dot2(bz.w, hp[4 * q + 3], az1);
          anh = dot2(bn.x, hp[4 * q + 0], anh);  an1 = dot2(bn.y, hp[4 * q + 1], an1);
          anh = dot2(bn.z, hp[4 * q + 2], anh);  an1 = dot2(bn.w, hp[4 * q + 3], an1);
        }
        float r = sigm(ar + ar1);
        float z = sigm(az + az1);
        float n = tanhf_fast(ani + r * (anh + an1));
        h = (1.0f - z) * n + z * h;
        BCAST(hp, h);                        // refresh broadcast (in-register)
      }
      ++e_next;
      if (e_next < necap) {
        s_next = sStep[e_next];
        v_cur = v_pipe;
        if (v_cur > 0) {
          const float* xp = X + (long)(v_cur - 1) * IN;
#pragma unroll
          for (int kk = 0; kk < 8; ++kk) xf[kk] = (kk < IN) ? xp[kk] : 0.0f;
        }
        v_pipe = (alive && e_next + 1 < necap) ? evrow[e_next + 1] : 0;
      } else {
        s_next = 0x7fffffff;
        v_cur = 0;
      }
    }

    if (alive)
      *hps = (f16)h;                         // h_rec (post-event, pre-ODE)
    hps += rowstride;

    // ---- phase A: r,z gates (weights + broadcasts all in registers) ----
    float ar0 = xr, ar1 = 0.f, ar2 = 0.f, ar3 = 0.f;
    float az0 = xz, az1 = 0.f, az2 = 0.f, az3 = 0.f;
#pragma unroll
    for (int q = 0; q < 8; ++q) {
      ar0 = dot2(WR[q].x, hp[4 * q + 0], ar0); ar1 = dot2(WR[q].y, hp[4 * q + 1], ar1);
      ar2 = dot2(WR[q].z, hp[4 * q + 2], ar2); ar3 = dot2(WR[q].w, hp[4 * q + 3], ar3);
      az0 = dot2(WZ[q].x, hp[4 * q + 0], az0); az1 = dot2(WZ[q].y, hp[4 * q + 1], az1);
      az2 = dot2(WZ[q].z, hp[4 * q + 2], az2); az3 = dot2(WZ[q].w, hp[4 * q + 3], az3);
    }
    float r = sigm((ar0 + ar1) + (ar2 + ar3));
    float z = sigm((az0 + az1) + (az2 + az3));

    // ---- phase B: u matvec (r*h broadcast in registers) ----
    float rh = r * h;
    unsigned rp[32];
    BCAST(rp, rh);
    float au0 = xh, au1 = 0.f, au2 = 0.f, au3 = 0.f;
#pragma unroll
    for (int q = 0; q < 8; ++q) {
      au0 = dot2(WU[q].x, rp[4 * q + 0], au0); au1 = dot2(WU[q].y, rp[4 * q + 1], au1);
      au2 = dot2(WU[q].z, rp[4 * q + 2], au2); au3 = dot2(WU[q].w, rp[4 * q + 3], au3);
    }
    float u = tanhf_fast((au0 + au1) + (au2 + au3));
    h = fmaf(DT_F * (1.0f - z), u - h, h);
    BCAST(hp, h);                            // next step's broadcast
  }

  if (alive)
    *hps = (f16)h;                           // h_last
}

// MFMA head (verified R9): out[row] = relu(h[row] @ W1^T + b1) @ W2^T + b2.
__global__ __launch_bounds__(256, 4) void head_mfma_kernel(
    const f16* __restrict__ hp16, const f16* __restrict__ w1P,
    const float* __restrict__ b1, const float* __restrict__ W2,
    const float* __restrict__ b2, float* __restrict__ out, long nrows)
{
  const int wq = threadIdx.x >> 6, lane = threadIdx.x & 63;
  const int col = lane & 15;
  const long rowbase = ((long)blockIdx.x * 4 + wq) * 64;   // 64 rows per wave

  f16x8 Wf[8][2];
#pragma unroll
  for (int t = 0; t < 8; ++t)
#pragma unroll
    for (int kf = 0; kf < 2; ++kf)
      Wf[t][kf] = ((const f16x8*)w1P)[(2 * t + kf) * 64 + lane];

  float b1v[8], w2a[8], w2b[8];
#pragma unroll
  for (int t = 0; t < 8; ++t) {
    b1v[t] = b1[16 * t + col];
    w2a[t] = W2[16 * t + col];
    w2b[t] = W2[128 + 16 * t + col];
  }
  const float b20 = b2[0], b21 = b2[1];

#pragma unroll 1
  for (int g = 0; g < 4; ++g) {
    long row0 = rowbase + g * 16;
    long arow = row0 + col;
    f16x8 aH0 = {0, 0, 0, 0, 0, 0, 0, 0}, aH1 = aH0;
    if (arow < nrows) {
      const f16x8* ap = (const f16x8*)(hp16 + arow * 64);
      aH0 = ap[lane >> 4];
      aH1 = ap[(lane >> 4) + 4];
    }
    float p0[4] = {0.f, 0.f, 0.f, 0.f}, p1[4] = {0.f, 0.f, 0.f, 0.f};
#pragma unroll
    for (int t = 0; t < 8; ++t) {
      f32x4 c = {0.f, 0.f, 0.f, 0.f};
      c = MFMA16(aH0, Wf[t][0], c);
      c = MFMA16(aH1, Wf[t][1], c);
#pragma unroll
      for (int i = 0; i < 4; ++i) {
        float o = fmaxf(c[i] + b1v[t], 0.0f);
        p0[i] = fmaf(o, w2a[t], p0[i]);
        p1[i] = fmaf(o, w2b[t], p1[i]);
      }
    }
#pragma unroll
    for (int off = 1; off < 16; off <<= 1) {
#pragma unroll
      for (int i = 0; i < 4; ++i) {
        p0[i] += __shfl_xor(p0[i], off);
        p1[i] += __shfl_xor(p1[i], off);
      }
    }
    if (col == 0) {
#pragma unroll
      for (int i = 0; i < 4; ++i) {
        long row = row0 + (lane >> 4) * 4 + i;
        if (row < nrows) {
          out[row * 2 + 0] = p0[i] + b20;
          out[row * 2 + 1] = p1[i] + b21;
        }
      }
    }
  }
}

extern "C" void kernel_launch(void* const* d_in, const int* in_sizes, int n_in,
                              void* d_out, int out_size, void* d_ws, size_t ws_size,
                              hipStream_t stream) {
  const float* time_uniq  = (const float*)d_in[0];
  const int*   time_ptr   = (const int*)d_in[1];
  const float* X          = (const float*)d_in[2];
  const int*   sample_ids = (const int*)d_in[3];
  const float* covs       = (const float*)d_in[4];
  const float* cov_W1     = (const float*)d_in[6];
  const float* cov_b1     = (const float*)d_in[7];
  const float* cov_W2     = (const float*)d_in[8];
  const float* cov_b2     = (const float*)d_in[9];
  const float* gb_Wih     = (const float*)d_in[10];
  const float* gb_Whh     = (const float*)d_in[11];
  const float* gb_bih     = (const float*)d_in[12];
  const float* gb_bhh     = (const float*)d_in[13];
  const float* gx_b       = (const float*)d_in[15];
  const float* ghr_W      = (const float*)d_in[16];
  const float* ghz_W      = (const float*)d_in[17];
  const float* ghh_W      = (const float*)d_in[18];
  const float* out_W1     = (const float*)d_in[19];
  const float* out_b1     = (const float*)d_in[20];
  const float* out_W2     = (const float*)d_in[21];
  const float* out_b2     = (const float*)d_in[22];

  int NE   = in_sizes[0];
  int TOT  = in_sizes[3];
  int IN   = in_sizes[2] / TOT;
  int CH   = in_sizes[7];
  int COV  = in_sizes[6] / CH;
  int B    = in_sizes[4] / COV;
  int OUTD = in_sizes[22];
  int n_steps = out_size / (B * OUTD) - 1;
  int OPE  = TOT / NE;

  char* ws = (char*)d_ws;
  int* evtabT = (int*)ws;                       // [B][NEC], transposed
  size_t evbytes = (size_t)B * NEC * sizeof(int);
  size_t off1 = (evbytes + 255) & ~(size_t)255;
  unsigned* odeP = (unsigned*)(ws + off1);
  unsigned* bayP = odeP + 3 * 64 * 32;
  unsigned* wihP = bayP + 3 * 64 * 32;
  size_t off2 = off1 + (((3 * 64 * 32 * 2 + 3 * 64 * 4) * sizeof(unsigned) + 255) & ~(size_t)255);
  f16* w1P = (f16*)(ws + off2);
  size_t off3 = off2 + ((16 * 512 * sizeof(f16) + 255) & ~(size_t)255);
  f16* hp16 = (f16*)(ws + off3);

  hipMemsetAsync(evtabT, 0, evbytes, stream);
  build_evtab_kernel<<<NE, 256, 0, stream>>>(sample_ids, time_ptr, evtabT, B, OPE);
  pack_pairs_kernel<<<24, 256, 0, stream>>>(ghr_W, ghz_W, ghh_W, gb_Whh, gb_Wih,
                                            odeP, bayP, wihP, IN);
  pack_head_kernel<<<16, 64, 0, stream>>>(out_W1, w1P);
  evolve_kernel<<<(B + 3) / 4, 256, 0, stream>>>(
      time_uniq, X, covs, cov_W1, cov_b1, cov_W2, cov_b2,
      gb_bih, gb_bhh, gx_b, odeP, bayP, wihP,
      evtabT, hp16, B, NE, n_steps, IN, COV);
  long nrows = (long)(n_steps + 1) * B;
  int hb = (int)((nrows + 255) / 256);
  head_mfma_kernel<<<hb, 256, 0, stream>>>(hp16, w1P, out_b1, out_W2, out_b2,
                                           (float*)d_out, nrows);
}

// Round 14
// 441.216 us; speedup vs baseline: 1.1322x; 1.1322x over previous
//
#include <hip/hip_runtime.h>

#define DT_F 0.01f
#define EPS_F 1e-5f
#define NEG_INF_I (-1073741824)
#define NEC 1024   // padded event capacity (stride of evtabT rows)

typedef _Float16 f16;
typedef _Float16 f16x2 __attribute__((ext_vector_type(2)));
typedef _Float16 f16x8 __attribute__((ext_vector_type(8)));
typedef float f32x4 __attribute__((ext_vector_type(4)));

#define MFMA16(a, b, c) __builtin_amdgcn_mfma_f32_16x16x32_f16((a), (b), (c), 0, 0, 0)

__device__ __forceinline__ float rl(float v, int l) {
  return __int_as_float(__builtin_amdgcn_readlane(__float_as_int(v), l));
}
__device__ __forceinline__ float sigm(float x) {
  float e = __builtin_amdgcn_exp2f(-1.442695041f * x);
  return __builtin_amdgcn_rcpf(1.0f + e);
}
__device__ __forceinline__ float tanhf_fast(float x) {
  float e = __builtin_amdgcn_exp2f(2.885390082f * x);
  return fmaf(-2.0f, __builtin_amdgcn_rcpf(e + 1.0f), 1.0f);
}
__device__ __forceinline__ float dot2(unsigned w, unsigned h, float acc) {
  return __builtin_amdgcn_fdot2(__builtin_bit_cast(f16x2, w),
                                __builtin_bit_cast(f16x2, h), acc, false);
}
__device__ __forceinline__ unsigned packf16(float a, float b) {
  return __builtin_bit_cast(unsigned, __builtin_amdgcn_cvt_pkrtz(a, b));
}
#define ANCH4(v) asm volatile("" : "+v"((v).x), "+v"((v).y), "+v"((v).z), "+v"((v).w))

// evtabT[sid*NEC + k] = (last obs index in event k's window with sample_ids==sid)+1, or 0.
__global__ void build_evtab_kernel(const int* __restrict__ sample_ids,
                                   const int* __restrict__ time_ptr,
                                   int* __restrict__ evtabT, int B, int ope) {
  int k = blockIdx.x;
  int base = time_ptr[k];
  for (int t = threadIdx.x; t < ope; t += blockDim.x) {
    int obs = base + t;
    int sid = sample_ids[obs];
    atomicMax(&evtabT[(long)sid * NEC + k], obs + 1);   // last occurrence wins
  }
}

// f16-pair packing (verified R7)
__global__ void pack_pairs_kernel(const float* __restrict__ ghr,
                                  const float* __restrict__ ghz,
                                  const float* __restrict__ ghh,
                                  const float* __restrict__ gbWhh,
                                  const float* __restrict__ gbWih,
                                  unsigned* __restrict__ odeP,
                                  unsigned* __restrict__ bayP,
                                  unsigned* __restrict__ wihP, int IN) {
  int idx = blockIdx.x * 256 + threadIdx.x;
  if (idx < 3 * 64 * 32) {
    int p = idx & 31, r = idx >> 5;
    int g = r >> 6, i = r & 63;
    const float* src = (g == 0) ? ghr : ((g == 1) ? ghz : ghh);
    odeP[idx] = packf16(src[i * 64 + 2 * p], src[i * 64 + 2 * p + 1]);
    bayP[idx] = packf16(gbWhh[r * 64 + 2 * p], gbWhh[r * 64 + 2 * p + 1]);
  }
  if (idx < 3 * 64 * 4) {
    int p = idx & 3, r = idx >> 2;
    float a = (2 * p < IN) ? gbWih[r * IN + 2 * p] : 0.0f;
    float b = (2 * p + 1 < IN) ? gbWih[r * IN + 2 * p + 1] : 0.0f;
    wihP[idx] = packf16(a, b);
  }
}

// W1 -> MFMA B-fragments (layout HW-verified in R5)
__global__ void pack_head_kernel(const float* __restrict__ W1, f16* __restrict__ w1P) {
  int f = blockIdx.x;       // 0..15
  int l = threadIdx.x;      // 0..63
  int t = f >> 1, kf = f & 1;
  int n = 16 * t + (l & 15);
  for (int j = 0; j < 8; ++j) {
    int k = 8 * (l >> 4) + j + 32 * kf;
    w1P[f * 512 + l * 8 + j] = (f16)W1[n * 64 + k];
  }
}

// ONE SAMPLE per 128-thread block. wave0 (master, setprio 1): r + rh (same-wave
// LDS RT) + u + events + h update, h-pairs CARRIED in registers across steps.
// wave1: z-gate + hpath stores (off critical path). 2 barriers/step (+1 fire).
__global__ __launch_bounds__(128, 2) void evolve_kernel(
    const float* __restrict__ time_uniq,
    const float* __restrict__ X,
    const float* __restrict__ covs,
    const float* __restrict__ cov_W1, const float* __restrict__ cov_b1,
    const float* __restrict__ cov_W2, const float* __restrict__ cov_b2,
    const float* __restrict__ gb_bih, const float* __restrict__ gb_bhh,
    const float* __restrict__ gx_b,
    const unsigned* __restrict__ odeP, const unsigned* __restrict__ bayP,
    const unsigned* __restrict__ wihP,
    const int* __restrict__ evtabT,
    f16* __restrict__ hp16,
    int B, int NE, int n_steps, int IN, int COV)
{
  __shared__ unsigned sBW[3 * 64 * 32];            // Bayes pairs, swizzled (24KB)
  __shared__ int sStep[1024];                      // event -> grid step (4KB)
  __shared__ int sEvt[1024];                       // this sample's event row (4KB)
  __shared__ __align__(16) f16 sHimg[64];          // h image (f16)
  __shared__ __align__(16) f16 sRHimg[64];         // r*h image (wave0-private)
  __shared__ float sZ[64];                         // z gate (wave1 -> wave0)

  const int tid = threadIdx.x;
  const int wid = tid >> 6, lane = tid & 63;
  const int b = blockIdx.x;
  const int necap = (NE < NEC) ? NE : NEC;

  for (int idx = tid; idx < 3 * 64 * 32; idx += 128) {
    int c = idx & 31, r = idx >> 5;
    int i = r & 63, s = c >> 2;
    sBW[r * 32 + (((s ^ (i & 7)) << 2) | (c & 3))] = bayP[idx];
  }
  for (int e = tid; e < necap; e += 128)
    sEvt[e] = evtabT[(long)b * NEC + e];
  if (wid == 0) {     // wave-parallel prefix-max event schedule (verified R6/R7)
    int pm = NEG_INF_I;
    int loc[16];
#pragma unroll
    for (int j = 0; j < 16; ++j) {
      int e = lane * 16 + j;
      int gv = NEG_INF_I;
      if (e < necap) {
        float tu = time_uniq[e];
        int k0 = (int)floorf((tu - EPS_F) * 100.0f) - 2;
        if (k0 < 0) k0 = 0;
        while ((float)k0 * DT_F + EPS_F < tu) ++k0;
        gv = k0 - e;
      }
      pm = max(pm, gv);
      loc[j] = pm;
    }
    int tot = pm;
#pragma unroll
    for (int off = 1; off < 64; off <<= 1) {
      int v = __shfl_up(tot, off);
      if (lane >= off) tot = max(tot, v);
    }
    int excl = __shfl_up(tot, 1);
    if (lane == 0) excl = NEG_INF_I;
#pragma unroll
    for (int j = 0; j < 16; ++j)
      sStep[lane * 16 + j] = lane * 16 + j + max(loc[j], excl);
  }
  if (wid == 0) {   // ---- h0 on wave0 ----
    float cacc = cov_b1[lane];
    for (int c = 0; c < COV; ++c)
      cacc = fmaf(covs[b * COV + c], cov_W1[lane * COV + c], cacc);
    float cl = fmaxf(cacc, 0.0f);
    float hacc = cov_b2[lane];
#pragma unroll
    for (int j = 0; j < 64; ++j)
      hacc = fmaf(rl(cl, j), cov_W2[lane * 64 + j], hacc);
    sHimg[lane] = (f16)tanhf_fast(hacc);
  }
  __syncthreads();   // init complete

  const uint4* odeQ = (const uint4*)odeP;
  const uint4* hq4 = (const uint4*)sHimg;
  const uint4* rq4 = (const uint4*)sRHimg;

  if (wid == 0) {
    // ============ WAVE 0: master (r + u + events + update) ============
    __builtin_amdgcn_s_setprio(1);
    uint4 WR[8], WU[8];
#pragma unroll
    for (int q = 0; q < 8; ++q) {
      WR[q] = odeQ[(0 * 64 + lane) * 8 + q];
      WU[q] = odeQ[(2 * 64 + lane) * 8 + q];
    }
#pragma unroll
    for (int q = 0; q < 8; ++q) { ANCH4(WR[q]); ANCH4(WU[q]); }
    const uint4* wihQ = (const uint4*)wihP;

    const float xr = gx_b[lane], xh = gx_b[128 + lane];
    const float crz_r = gb_bih[lane] + gb_bhh[lane];
    const float crz_z = gb_bih[64 + lane] + gb_bhh[64 + lane];
    const float bihn = gb_bih[128 + lane], bhhn = gb_bhh[128 + lane];

    float h = (float)sHimg[lane];
    uint4 hpre[8];                            // carried h-pairs (same-wave data)
#pragma unroll
    for (int q = 0; q < 8; ++q) hpre[q] = hq4[q];

    int e_next = 0, s_next = 0x7fffffff, v_cur = 0, v_pipe = 0;
    float xf[8];
#pragma unroll
    for (int kk = 0; kk < 8; ++kk) xf[kk] = 0.0f;
    if (necap > 0) {
      s_next = sStep[0];
      v_cur = sEvt[0];
      if (v_cur > 0) {
        const float* xp = X + (long)(v_cur - 1) * IN;
#pragma unroll
        for (int kk = 0; kk < 8; ++kk) xf[kk] = (kk < IN) ? xp[kk] : 0.0f;
      }
      v_pipe = (necap > 1) ? sEvt[1] : 0;
    }

#pragma unroll 1
    for (int k = 0; k < n_steps; ++k) {
      if (k == s_next) {
        const bool fire = (v_cur > 0);
        if (fire) {
          // gru_bayes on carried pairs (pre-event h) — zero LDS h-reads
          unsigned xp0 = packf16(xf[0], xf[1]), xp1 = packf16(xf[2], xf[3]);
          unsigned xp2 = packf16(xf[4], xf[5]), xp3 = packf16(xf[6], xf[7]);
          uint4 wxr = wihQ[lane], wxz = wihQ[64 + lane], wxn = wihQ[128 + lane];
          float ar = crz_r, az = crz_z, anh = bhhn, ani = bihn;
          ar = dot2(wxr.x, xp0, ar); ar = dot2(wxr.y, xp1, ar);
          ar = dot2(wxr.z, xp2, ar); ar = dot2(wxr.w, xp3, ar);
          az = dot2(wxz.x, xp0, az); az = dot2(wxz.y, xp1, az);
          az = dot2(wxz.z, xp2, az); az = dot2(wxz.w, xp3, az);
          ani = dot2(wxn.x, xp0, ani); ani = dot2(wxn.y, xp1, ani);
          ani = dot2(wxn.z, xp2, ani); ani = dot2(wxn.w, xp3, ani);
          float ar1 = 0.f, az1 = 0.f, an1 = 0.f;
#pragma unroll
          for (int q = 0; q < 8; ++q) {
            int sw = ((q ^ (lane & 7)) << 2);
            uint4 br = *(const uint4*)&sBW[(0 * 64 + lane) * 32 + sw];
            uint4 bz = *(const uint4*)&sBW[(1 * 64 + lane) * 32 + sw];
            uint4 bn = *(const uint4*)&sBW[(2 * 64 + lane) * 32 + sw];
            ar  = dot2(br.x, hpre[q].x, ar);   ar1 = dot2(br.y, hpre[q].y, ar1);
            ar  = dot2(br.z, hpre[q].z, ar);   ar1 = dot2(br.w, hpre[q].w, ar1);
            az  = dot2(bz.x, hpre[q].x, az);   az1 = dot2(bz.y, hpre[q].y, az1);
            az  = dot2(bz.z, hpre[q].z, az);   az1 = dot2(bz.w, hpre[q].w, az1);
            anh = dot2(bn.x, hpre[q].x, anh);  an1 = dot2(bn.y, hpre[q].y, an1);
            anh = dot2(bn.z, hpre[q].z, anh);  an1 = dot2(bn.w, hpre[q].w, an1);
          }
          float r = sigm(ar + ar1);
          float z = sigm(az + az1);
          float n = tanhf_fast(ani + r * (anh + an1));
          h = (1.0f - z) * n + z * h;
          sHimg[lane] = (f16)h;
#pragma unroll
          for (int q = 0; q < 8; ++q) hpre[q] = hq4[q];   // same-wave refresh
        }
        ++e_next;
        if (e_next < necap) {
          s_next = sStep[e_next];
          v_cur = v_pipe;
          if (v_cur > 0) {
            const float* xp = X + (long)(v_cur - 1) * IN;
#pragma unroll
            for (int kk = 0; kk < 8; ++kk) xf[kk] = (kk < IN) ? xp[kk] : 0.0f;
          }
          v_pipe = (e_next + 1 < necap) ? sEvt[e_next + 1] : 0;
        } else {
          s_next = 0x7fffffff;
          v_cur = 0;
        }
        if (fire) __syncthreads();            // B_e: post-event h visible to wave1
      }

      // ---- r gate (carried pairs, no LDS) ----
      float ar0 = xr, ar1 = 0.f, ar2 = 0.f, ar3 = 0.f;
#pragma unroll
      for (int q = 0; q < 8; ++q) {
        ar0 = dot2(WR[q].x, hpre[q].x, ar0); ar1 = dot2(WR[q].y, hpre[q].y, ar1);
        ar2 = dot2(WR[q].z, hpre[q].z, ar2); ar3 = dot2(WR[q].w, hpre[q].w, ar3);
      }
      float r = sigm((ar0 + ar1) + (ar2 + ar3));

      // ---- rh: the only in-chain LDS round trip (same-wave) ----
      sRHimg[lane] = (f16)(r * h);
      float au0 = xh, au1 = 0.f, au2 = 0.f, au3 = 0.f;
#pragma unroll
      for (int q = 0; q < 8; ++q) {
        uint4 rp = rq4[q];
        au0 = dot2(WU[q].x, rp.x, au0); au1 = dot2(WU[q].y, rp.y, au1);
        au2 = dot2(WU[q].z, rp.z, au2); au3 = dot2(WU[q].w, rp.w, au3);
      }
      __syncthreads();                        // B_z: z from wave1 ready (no wait)
      float zv = sZ[lane];
      float u = tanhf_fast((au0 + au1) + (au2 + au3));
      h = fmaf(DT_F * (1.0f - zv), u - h, h);
      sHimg[lane] = (f16)h;
#pragma unroll
      for (int q = 0; q < 8; ++q) hpre[q] = hq4[q];   // carry into next step
      __syncthreads();                        // B2: new h visible to wave1
    }
  } else {
    // ============ WAVE 1: z producer + hpath stores ============
    uint4 WZ[8];
#pragma unroll
    for (int q = 0; q < 8; ++q) WZ[q] = odeQ[(1 * 64 + lane) * 8 + q];
#pragma unroll
    for (int q = 0; q < 8; ++q) ANCH4(WZ[q]);
    const float xz = gx_b[64 + lane];

    f16* hps = hp16 + (long)b * 64 + lane;
    const long rowstride = (long)B * 64;

    int e_next = 0, s_next = 0x7fffffff, v_cur = 0, v_pipe = 0;
    if (necap > 0) {
      s_next = sStep[0];
      v_cur = sEvt[0];
      v_pipe = (necap > 1) ? sEvt[1] : 0;
    }

#pragma unroll 1
    for (int k = 0; k < n_steps; ++k) {
      if (k == s_next) {
        const bool fire = (v_cur > 0);
        ++e_next;
        if (e_next < necap) {
          s_next = sStep[e_next];
          v_cur = v_pipe;
          v_pipe = (e_next + 1 < necap) ? sEvt[e_next + 1] : 0;
        } else {
          s_next = 0x7fffffff;
          v_cur = 0;
        }
        if (fire) __syncthreads();            // B_e
      }

      // h_rec store (post-event, pre-ODE) + z gate from LDS h
      f16 hraw = sHimg[lane];
      *hps = hraw;
      hps += rowstride;

      float az0 = xz, az1 = 0.f, az2 = 0.f, az3 = 0.f;
#pragma unroll
      for (int q = 0; q < 8; ++q) {
        uint4 hh = hq4[q];
        az0 = dot2(WZ[q].x, hh.x, az0); az1 = dot2(WZ[q].y, hh.y, az1);
        az2 = dot2(WZ[q].z, hh.z, az2); az3 = dot2(WZ[q].w, hh.w, az3);
      }
      sZ[lane] = sigm((az0 + az1) + (az2 + az3));
      __syncthreads();                        // B_z: z delivered
      __syncthreads();                        // B2: wave0's new h written
    }
    *hps = sHimg[lane];                       // h_last
  }
}

// MFMA head (verified R9): out[row] = relu(h[row] @ W1^T + b1) @ W2^T + b2.
__global__ __launch_bounds__(256, 4) void head_mfma_kernel(
    const f16* __restrict__ hp16, const f16* __restrict__ w1P,
    const float* __restrict__ b1, const float* __restrict__ W2,
    const float* __restrict__ b2, float* __restrict__ out, long nrows)
{
  const int wq = threadIdx.x >> 6, lane = threadIdx.x & 63;
  const int col = lane & 15;
  const long rowbase = ((long)blockIdx.x * 4 + wq) * 64;   // 64 rows per wave

  f16x8 Wf[8][2];
#pragma unroll
  for (int t = 0; t < 8; ++t)
#pragma unroll
    for (int kf = 0; kf < 2; ++kf)
      Wf[t][kf] = ((const f16x8*)w1P)[(2 * t + kf) * 64 + lane];

  float b1v[8], w2a[8], w2b[8];
#pragma unroll
  for (int t = 0; t < 8; ++t) {
    b1v[t] = b1[16 * t + col];
    w2a[t] = W2[16 * t + col];
    w2b[t] = W2[128 + 16 * t + col];
  }
  const float b20 = b2[0], b21 = b2[1];

#pragma unroll 1
  for (int g = 0; g < 4; ++g) {
    long row0 = rowbase + g * 16;
    long arow = row0 + col;
    f16x8 aH0 = {0, 0, 0, 0, 0, 0, 0, 0}, aH1 = aH0;
    if (arow < nrows) {
      const f16x8* ap = (const f16x8*)(hp16 + arow * 64);
      aH0 = ap[lane >> 4];
      aH1 = ap[(lane >> 4) + 4];
    }
    float p0[4] = {0.f, 0.f, 0.f, 0.f}, p1[4] = {0.f, 0.f, 0.f, 0.f};
#pragma unroll
    for (int t = 0; t < 8; ++t) {
      f32x4 c = {0.f, 0.f, 0.f, 0.f};
      c = MFMA16(aH0, Wf[t][0], c);
      c = MFMA16(aH1, Wf[t][1], c);
#pragma unroll
      for (int i = 0; i < 4; ++i) {
        float o = fmaxf(c[i] + b1v[t], 0.0f);
        p0[i] = fmaf(o, w2a[t], p0[i]);
        p1[i] = fmaf(o, w2b[t], p1[i]);
      }
    }
#pragma unroll
    for (int off = 1; off < 16; off <<= 1) {
#pragma unroll
      for (int i = 0; i < 4; ++i) {
        p0[i] += __shfl_xor(p0[i], off);
        p1[i] += __shfl_xor(p1[i], off);
      }
    }
    if (col == 0) {
#pragma unroll
      for (int i = 0; i < 4; ++i) {
        long row = row0 + (lane >> 4) * 4 + i;
        if (row < nrows) {
          out[row * 2 + 0] = p0[i] + b20;
          out[row * 2 + 1] = p1[i] + b21;
        }
      }
    }
  }
}

extern "C" void kernel_launch(void* const* d_in, const int* in_sizes, int n_in,
                              void* d_out, int out_size, void* d_ws, size_t ws_size,
                              hipStream_t stream) {
  const float* time_uniq  = (const float*)d_in[0];
  const int*   time_ptr   = (const int*)d_in[1];
  const float* X          = (const float*)d_in[2];
  const int*   sample_ids = (const int*)d_in[3];
  const float* covs       = (const float*)d_in[4];
  const float* cov_W1     = (const float*)d_in[6];
  const float* cov_b1     = (const float*)d_in[7];
  const float* cov_W2     = (const float*)d_in[8];
  const float* cov_b2     = (const float*)d_in[9];
  const float* gb_Wih     = (const float*)d_in[10];
  const float* gb_Whh     = (const float*)d_in[11];
  const float* gb_bih     = (const float*)d_in[12];
  const float* gb_bhh     = (const float*)d_in[13];
  const float* gx_b       = (const float*)d_in[15];
  const float* ghr_W      = (const float*)d_in[16];
  const float* ghz_W      = (const float*)d_in[17];
  const float* ghh_W      = (const float*)d_in[18];
  const float* out_W1     = (const float*)d_in[19];
  const float* out_b1     = (const float*)d_in[20];
  const float* out_W2     = (const float*)d_in[21];
  const float* out_b2     = (const float*)d_in[22];

  int NE   = in_sizes[0];
  int TOT  = in_sizes[3];
  int IN   = in_sizes[2] / TOT;
  int CH   = in_sizes[7];
  int COV  = in_sizes[6] / CH;
  int B    = in_sizes[4] / COV;
  int OUTD = in_sizes[22];
  int n_steps = out_size / (B * OUTD) - 1;
  int OPE  = TOT / NE;

  char* ws = (char*)d_ws;
  int* evtabT = (int*)ws;                       // [B][NEC], transposed
  size_t evbytes = (size_t)B * NEC * sizeof(int);
  size_t off1 = (evbytes + 255) & ~(size_t)255;
  unsigned* odeP = (unsigned*)(ws + off1);
  unsigned* bayP = odeP + 3 * 64 * 32;
  unsigned* wihP = bayP + 3 * 64 * 32;
  size_t off2 = off1 + (((3 * 64 * 32 * 2 + 3 * 64 * 4) * sizeof(unsigned) + 255) & ~(size_t)255);
  f16* w1P = (f16*)(ws + off2);
  size_t off3 = off2 + ((16 * 512 * sizeof(f16) + 255) & ~(size_t)255);
  f16* hp16 = (f16*)(ws + off3);

  hipMemsetAsync(evtabT, 0, evbytes, stream);
  build_evtab_kernel<<<NE, 256, 0, stream>>>(sample_ids, time_ptr, evtabT, B, OPE);
  pack_pairs_kernel<<<24, 256, 0, stream>>>(ghr_W, ghz_W, ghh_W, gb_Whh, gb_Wih,
                                            odeP, bayP, wihP, IN);
  pack_head_kernel<<<16, 64, 0, stream>>>(out_W1, w1P);
  evolve_kernel<<<B, 128, 0, stream>>>(
      time_uniq, X, covs, cov_W1, cov_b1, cov_W2, cov_b2,
      gb_bih, gb_bhh, gx_b, odeP, bayP, wihP,
      evtabT, hp16, B, NE, n_steps, IN, COV);
  long nrows = (long)(n_steps + 1) * B;
  int hb = (int)((nrows + 255) / 256);
  head_mfma_kernel<<<hb, 256, 0, stream>>>(hp16, w1P, out_b1, out_W2, out_b2,
                                           (float*)d_out, nrows);
}

// Round 15
// 432.850 us; speedup vs baseline: 1.1540x; 1.0193x over previous
//
#include <hip/hip_runtime.h>

#define DT_F 0.01f
#define EPS_F 1e-5f
#define NEG_INF_I (-1073741824)
#define NEC 1024   // padded event capacity (stride of evtabT rows)

typedef _Float16 f16;
typedef _Float16 f16x2 __attribute__((ext_vector_type(2)));
typedef _Float16 f16x8 __attribute__((ext_vector_type(8)));
typedef float f32x4 __attribute__((ext_vector_type(4)));

#define MFMA16(a, b, c) __builtin_amdgcn_mfma_f32_16x16x32_f16((a), (b), (c), 0, 0, 0)

__device__ __forceinline__ float rl(float v, int l) {
  return __int_as_float(__builtin_amdgcn_readlane(__float_as_int(v), l));
}
__device__ __forceinline__ float sigm(float x) {
  float e = __builtin_amdgcn_exp2f(-1.442695041f * x);
  return __builtin_amdgcn_rcpf(1.0f + e);
}
__device__ __forceinline__ float tanhf_fast(float x) {
  float e = __builtin_amdgcn_exp2f(2.885390082f * x);
  return fmaf(-2.0f, __builtin_amdgcn_rcpf(e + 1.0f), 1.0f);
}
__device__ __forceinline__ float dot2(unsigned w, unsigned h, float acc) {
  return __builtin_amdgcn_fdot2(__builtin_bit_cast(f16x2, w),
                                __builtin_bit_cast(f16x2, h), acc, false);
}
__device__ __forceinline__ unsigned packf16(float a, float b) {
  return __builtin_bit_cast(unsigned, __builtin_amdgcn_cvt_pkrtz(a, b));
}
#define ANCH4(v) asm volatile("" : "+v"((v).x), "+v"((v).y), "+v"((v).z), "+v"((v).w))

// evtabT[sid*NEC + k] = (last obs index in event k's window with sample_ids==sid)+1, or 0.
// TRANSPOSED layout: per-sample event row is contiguous (coalesced staging).
__global__ void build_evtab_kernel(const int* __restrict__ sample_ids,
                                   const int* __restrict__ time_ptr,
                                   int* __restrict__ evtabT, int B, int ope) {
  int k = blockIdx.x;
  int base = time_ptr[k];
  for (int t = threadIdx.x; t < ope; t += blockDim.x) {
    int obs = base + t;
    int sid = sample_ids[obs];
    atomicMax(&evtabT[(long)sid * NEC + k], obs + 1);   // last occurrence wins
  }
}

// f16-pair packing (verified R7)
__global__ void pack_pairs_kernel(const float* __restrict__ ghr,
                                  const float* __restrict__ ghz,
                                  const float* __restrict__ ghh,
                                  const float* __restrict__ gbWhh,
                                  const float* __restrict__ gbWih,
                                  unsigned* __restrict__ odeP,
                                  unsigned* __restrict__ bayP,
                                  unsigned* __restrict__ wihP, int IN) {
  int idx = blockIdx.x * 256 + threadIdx.x;
  if (idx < 3 * 64 * 32) {
    int p = idx & 31, r = idx >> 5;
    int g = r >> 6, i = r & 63;
    const float* src = (g == 0) ? ghr : ((g == 1) ? ghz : ghh);
    odeP[idx] = packf16(src[i * 64 + 2 * p], src[i * 64 + 2 * p + 1]);
    bayP[idx] = packf16(gbWhh[r * 64 + 2 * p], gbWhh[r * 64 + 2 * p + 1]);
  }
  if (idx < 3 * 64 * 4) {
    int p = idx & 3, r = idx >> 2;
    float a = (2 * p < IN) ? gbWih[r * IN + 2 * p] : 0.0f;
    float b = (2 * p + 1 < IN) ? gbWih[r * IN + 2 * p + 1] : 0.0f;
    wihP[idx] = packf16(a, b);
  }
}

// W1 -> MFMA B-fragments (layout HW-verified in R5)
__global__ void pack_head_kernel(const float* __restrict__ W1, f16* __restrict__ w1P) {
  int f = blockIdx.x;       // 0..15
  int l = threadIdx.x;      // 0..63
  int t = f >> 1, kf = f & 1;
  int n = 16 * t + (l & 15);
  for (int j = 0; j < 8; ++j) {
    int k = 8 * (l >> 4) + j + 32 * kf;
    w1P[f * 512 + l * 8 + j] = (f16)W1[n * 64 + k];
  }
}

// ONE SAMPLE per 128-thread block = 2048 waves. wave0: state master (events,
// z, u, h update). wave1: r producer + ALL hpath stores. 2 barriers/step.
__global__ __launch_bounds__(128, 2) void evolve_kernel(
    const float* __restrict__ time_uniq,
    const float* __restrict__ X,
    const float* __restrict__ covs,
    const float* __restrict__ cov_W1, const float* __restrict__ cov_b1,
    const float* __restrict__ cov_W2, const float* __restrict__ cov_b2,
    const float* __restrict__ gb_bih, const float* __restrict__ gb_bhh,
    const float* __restrict__ gx_b,
    const unsigned* __restrict__ odeP, const unsigned* __restrict__ bayP,
    const unsigned* __restrict__ wihP,
    const int* __restrict__ evtabT,
    f16* __restrict__ hp16,
    int B, int NE, int n_steps, int IN, int COV)
{
  __shared__ unsigned sBW[3 * 64 * 32];            // Bayes pairs, swizzled (24KB)
  __shared__ int sStep[1024];                      // event -> grid step (4KB)
  __shared__ int sEvt[1024];                       // this sample's event row (4KB)
  __shared__ __align__(16) f16 sHimg[64];          // h image (f16)
  __shared__ __align__(16) f16 sRHimg[64];         // r*h image (f16)

  const int tid = threadIdx.x;
  const int wid = tid >> 6, lane = tid & 63;
  const int b = blockIdx.x;
  const int necap = (NE < NEC) ? NE : NEC;

  for (int idx = tid; idx < 3 * 64 * 32; idx += 128) {
    int c = idx & 31, r = idx >> 5;
    int i = r & 63, s = c >> 2;
    sBW[r * 32 + (((s ^ (i & 7)) << 2) | (c & 3))] = bayP[idx];
  }
  // coalesced event-row staging (evtabT row is contiguous)
  for (int e = tid; e < necap; e += 128)
    sEvt[e] = evtabT[(long)b * NEC + e];
  if (wid == 0) {     // wave-parallel prefix-max event schedule (verified R6/R7)
    int pm = NEG_INF_I;
    int loc[16];
#pragma unroll
    for (int j = 0; j < 16; ++j) {
      int e = lane * 16 + j;
      int gv = NEG_INF_I;
      if (e < necap) {
        float tu = time_uniq[e];
        int k0 = (int)floorf((tu - EPS_F) * 100.0f) - 2;
        if (k0 < 0) k0 = 0;
        while ((float)k0 * DT_F + EPS_F < tu) ++k0;
        gv = k0 - e;
      }
      pm = max(pm, gv);
      loc[j] = pm;
    }
    int tot = pm;
#pragma unroll
    for (int off = 1; off < 64; off <<= 1) {
      int v = __shfl_up(tot, off);
      if (lane >= off) tot = max(tot, v);
    }
    int excl = __shfl_up(tot, 1);
    if (lane == 0) excl = NEG_INF_I;
#pragma unroll
    for (int j = 0; j < 16; ++j)
      sStep[lane * 16 + j] = lane * 16 + j + max(loc[j], excl);
  }
  if (wid == 0) {   // ---- h0 on wave0 ----
    float cacc = cov_b1[lane];
    for (int c = 0; c < COV; ++c)
      cacc = fmaf(covs[b * COV + c], cov_W1[lane * COV + c], cacc);
    float cl = fmaxf(cacc, 0.0f);
    float hacc = cov_b2[lane];
#pragma unroll
    for (int j = 0; j < 64; ++j)
      hacc = fmaf(rl(cl, j), cov_W2[lane * 64 + j], hacc);
    sHimg[lane] = (f16)tanhf_fast(hacc);
  }
  __syncthreads();   // init complete

  const uint4* odeQ = (const uint4*)odeP;
  const uint4* hq4 = (const uint4*)sHimg;
  const uint4* rq4 = (const uint4*)sRHimg;

  if (wid == 0) {
    // ================= WAVE 0: state master (no global stores) =================
    uint4 WZ[8], WU[8];
#pragma unroll
    for (int q = 0; q < 8; ++q) {
      WZ[q] = odeQ[(1 * 64 + lane) * 8 + q];
      WU[q] = odeQ[(2 * 64 + lane) * 8 + q];
    }
#pragma unroll
    for (int q = 0; q < 8; ++q) { ANCH4(WZ[q]); ANCH4(WU[q]); }
    const uint4* wihQ = (const uint4*)wihP;

    const float xz = gx_b[64 + lane], xh = gx_b[128 + lane];
    const float crz_r = gb_bih[lane] + gb_bhh[lane];
    const float crz_z = gb_bih[64 + lane] + gb_bhh[64 + lane];
    const float bihn = gb_bih[128 + lane], bhhn = gb_bhh[128 + lane];

    float h = (float)sHimg[lane];

    int e_next = 0, s_next = 0x7fffffff, v_cur = 0, v_pipe = 0;
    float xf[8];
#pragma unroll
    for (int kk = 0; kk < 8; ++kk) xf[kk] = 0.0f;
    if (necap > 0) {
      s_next = sStep[0];
      v_cur = sEvt[0];
      if (v_cur > 0) {
        const float* xp = X + (long)(v_cur - 1) * IN;
#pragma unroll
        for (int kk = 0; kk < 8; ++kk) xf[kk] = (kk < IN) ? xp[kk] : 0.0f;
      }
      v_pipe = (necap > 1) ? sEvt[1] : 0;
    }

#pragma unroll 1
    for (int k = 0; k < n_steps; ++k) {
      if (k == s_next) {
        const bool fire = (v_cur > 0);
        if (fire) {
          unsigned xp0 = packf16(xf[0], xf[1]), xp1 = packf16(xf[2], xf[3]);
          unsigned xp2 = packf16(xf[4], xf[5]), xp3 = packf16(xf[6], xf[7]);
          uint4 wxr = wihQ[lane], wxz = wihQ[64 + lane], wxn = wihQ[128 + lane];
          float ar = crz_r, az = crz_z, anh = bhhn, ani = bihn;
          ar = dot2(wxr.x, xp0, ar); ar = dot2(wxr.y, xp1, ar);
          ar = dot2(wxr.z, xp2, ar); ar = dot2(wxr.w, xp3, ar);
          az = dot2(wxz.x, xp0, az); az = dot2(wxz.y, xp1, az);
          az = dot2(wxz.z, xp2, az); az = dot2(wxz.w, xp3, az);
          ani = dot2(wxn.x, xp0, ani); ani = dot2(wxn.y, xp1, ani);
          ani = dot2(wxn.z, xp2, ani); ani = dot2(wxn.w, xp3, ani);
          float ar1 = 0.f, az1 = 0.f, an1 = 0.f;
#pragma unroll
          for (int q = 0; q < 8; ++q) {
            uint4 hh = hq4[q];
            int sw = ((q ^ (lane & 7)) << 2);
            uint4 br = *(const uint4*)&sBW[(0 * 64 + lane) * 32 + sw];
            uint4 bz = *(const uint4*)&sBW[(1 * 64 + lane) * 32 + sw];
            uint4 bn = *(const uint4*)&sBW[(2 * 64 + lane) * 32 + sw];
            ar  = dot2(br.x, hh.x, ar);   ar1 = dot2(br.y, hh.y, ar1);
            ar  = dot2(br.z, hh.z, ar);   ar1 = dot2(br.w, hh.w, ar1);
            az  = dot2(bz.x, hh.x, az);   az1 = dot2(bz.y, hh.y, az1);
            az  = dot2(bz.z, hh.z, az);   az1 = dot2(bz.w, hh.w, az1);
            anh = dot2(bn.x, hh.x, anh);  an1 = dot2(bn.y, hh.y, an1);
            anh = dot2(bn.z, hh.z, anh);  an1 = dot2(bn.w, hh.w, an1);
          }
          float r = sigm(ar + ar1);
          float z = sigm(az + az1);
          float n = tanhf_fast(ani + r * (anh + an1));
          h = (1.0f - z) * n + z * h;
          sHimg[lane] = (f16)h;
        }
        ++e_next;
        if (e_next < necap) {
          s_next = sStep[e_next];
          v_cur = v_pipe;
          if (v_cur > 0) {
            const float* xp = X + (long)(v_cur - 1) * IN;
#pragma unroll
            for (int kk = 0; kk < 8; ++kk) xf[kk] = (kk < IN) ? xp[kk] : 0.0f;
          }
          v_pipe = (e_next + 1 < necap) ? sEvt[e_next + 1] : 0;
        } else {
          s_next = 0x7fffffff;
          v_cur = 0;
        }
        if (fire) __syncthreads();           // event image ready
      }

      // z gate
      float az0 = xz, az1 = 0.f, az2 = 0.f, az3 = 0.f;
#pragma unroll
      for (int q = 0; q < 8; ++q) {
        uint4 hp = hq4[q];
        az0 = dot2(WZ[q].x, hp.x, az0); az1 = dot2(WZ[q].y, hp.y, az1);
        az2 = dot2(WZ[q].z, hp.z, az2); az3 = dot2(WZ[q].w, hp.w, az3);
      }
      float z = sigm((az0 + az1) + (az2 + az3));
      __syncthreads();                       // B1: rh image ready

      float au0 = xh, au1 = 0.f, au2 = 0.f, au3 = 0.f;
#pragma unroll
      for (int q = 0; q < 8; ++q) {
        uint4 rp = rq4[q];
        au0 = dot2(WU[q].x, rp.x, au0); au1 = dot2(WU[q].y, rp.y, au1);
        au2 = dot2(WU[q].z, rp.z, au2); au3 = dot2(WU[q].w, rp.w, au3);
      }
      float u = tanhf_fast((au0 + au1) + (au2 + au3));
      h = fmaf(DT_F * (1.0f - z), u - h, h);
      sHimg[lane] = (f16)h;
      __syncthreads();                       // B2: h image ready
    }
  } else {
    // ========= WAVE 1: r producer + hpath stores =========
    uint4 WR[8];
#pragma unroll
    for (int q = 0; q < 8; ++q) WR[q] = odeQ[(0 * 64 + lane) * 8 + q];
#pragma unroll
    for (int q = 0; q < 8; ++q) ANCH4(WR[q]);
    const float xr = gx_b[lane];

    f16* hps = hp16 + (long)b * 64 + lane;
    const long rowstride = (long)B * 64;

    int e_next = 0, s_next = 0x7fffffff, v_cur = 0, v_pipe = 0;
    if (necap > 0) {
      s_next = sStep[0];
      v_cur = sEvt[0];
      v_pipe = (necap > 1) ? sEvt[1] : 0;
    }

#pragma unroll 1
    for (int k = 0; k < n_steps; ++k) {
      if (k == s_next) {
        const bool fire = (v_cur > 0);
        ++e_next;
        if (e_next < necap) {
          s_next = sStep[e_next];
          v_cur = v_pipe;
          v_pipe = (e_next + 1 < necap) ? sEvt[e_next + 1] : 0;
        } else {
          s_next = 0x7fffffff;
          v_cur = 0;
        }
        if (fire) __syncthreads();           // event image ready
      }

      // h_rec = post-event, pre-ODE h (this wave reads it anyway for rh)
      f16 hraw = sHimg[lane];
      *hps = hraw;                           // global store off the master chain
      hps += rowstride;
      float hf = (float)hraw;

      // r gate
      float ar0 = xr, ar1 = 0.f, ar2 = 0.f, ar3 = 0.f;
#pragma unroll
      for (int q = 0; q < 8; ++q) {
        uint4 hp = hq4[q];
        ar0 = dot2(WR[q].x, hp.x, ar0); ar1 = dot2(WR[q].y, hp.y, ar1);
        ar2 = dot2(WR[q].z, hp.z, ar2); ar3 = dot2(WR[q].w, hp.w, ar3);
      }
      float r = sigm((ar0 + ar1) + (ar2 + ar3));
      sRHimg[lane] = (f16)(r * hf);
      __syncthreads();                       // B1: rh image ready
      __syncthreads();                       // B2: h image ready
    }
    *hps = sHimg[lane];                      // h_last
  }
}

// MFMA head (verified R9): out[row] = relu(h[row] @ W1^T + b1) @ W2^T + b2.
__global__ __launch_bounds__(256, 4) void head_mfma_kernel(
    const f16* __restrict__ hp16, const f16* __restrict__ w1P,
    const float* __restrict__ b1, const float* __restrict__ W2,
    const float* __restrict__ b2, float* __restrict__ out, long nrows)
{
  const int wq = threadIdx.x >> 6, lane = threadIdx.x & 63;
  const int col = lane & 15;
  const long rowbase = ((long)blockIdx.x * 4 + wq) * 64;   // 64 rows per wave

  f16x8 Wf[8][2];
#pragma unroll
  for (int t = 0; t < 8; ++t)
#pragma unroll
    for (int kf = 0; kf < 2; ++kf)
      Wf[t][kf] = ((const f16x8*)w1P)[(2 * t + kf) * 64 + lane];

  float b1v[8], w2a[8], w2b[8];
#pragma unroll
  for (int t = 0; t < 8; ++t) {
    b1v[t] = b1[16 * t + col];
    w2a[t] = W2[16 * t + col];
    w2b[t] = W2[128 + 16 * t + col];
  }
  const float b20 = b2[0], b21 = b2[1];

#pragma unroll 1
  for (int g = 0; g < 4; ++g) {
    long row0 = rowbase + g * 16;
    long arow = row0 + col;
    f16x8 aH0 = {0, 0, 0, 0, 0, 0, 0, 0}, aH1 = aH0;
    if (arow < nrows) {
      const f16x8* ap = (const f16x8*)(hp16 + arow * 64);
      aH0 = ap[lane >> 4];
      aH1 = ap[(lane >> 4) + 4];
    }
    float p0[4] = {0.f, 0.f, 0.f, 0.f}, p1[4] = {0.f, 0.f, 0.f, 0.f};
#pragma unroll
    for (int t = 0; t < 8; ++t) {
      f32x4 c = {0.f, 0.f, 0.f, 0.f};
      c = MFMA16(aH0, Wf[t][0], c);
      c = MFMA16(aH1, Wf[t][1], c);
#pragma unroll
      for (int i = 0; i < 4; ++i) {
        float o = fmaxf(c[i] + b1v[t], 0.0f);
        p0[i] = fmaf(o, w2a[t], p0[i]);
        p1[i] = fmaf(o, w2b[t], p1[i]);
      }
    }
#pragma unroll
    for (int off = 1; off < 16; off <<= 1) {
#pragma unroll
      for (int i = 0; i < 4; ++i) {
        p0[i] += __shfl_xor(p0[i], off);
        p1[i] += __shfl_xor(p1[i], off);
      }
    }
    if (col == 0) {
#pragma unroll
      for (int i = 0; i < 4; ++i) {
        long row = row0 + (lane >> 4) * 4 + i;
        if (row < nrows) {
          out[row * 2 + 0] = p0[i] + b20;
          out[row * 2 + 1] = p1[i] + b21;
        }
      }
    }
  }
}

extern "C" void kernel_launch(void* const* d_in, const int* in_sizes, int n_in,
                              void* d_out, int out_size, void* d_ws, size_t ws_size,
                              hipStream_t stream) {
  const float* time_uniq  = (const float*)d_in[0];
  const int*   time_ptr   = (const int*)d_in[1];
  const float* X          = (const float*)d_in[2];
  const int*   sample_ids = (const int*)d_in[3];
  const float* covs       = (const float*)d_in[4];
  const float* cov_W1     = (const float*)d_in[6];
  const float* cov_b1     = (const float*)d_in[7];
  const float* cov_W2     = (const float*)d_in[8];
  const float* cov_b2     = (const float*)d_in[9];
  const float* gb_Wih     = (const float*)d_in[10];
  const float* gb_Whh     = (const float*)d_in[11];
  const float* gb_bih     = (const float*)d_in[12];
  const float* gb_bhh     = (const float*)d_in[13];
  const float* gx_b       = (const float*)d_in[15];
  const float* ghr_W      = (const float*)d_in[16];
  const float* ghz_W      = (const float*)d_in[17];
  const float* ghh_W      = (const float*)d_in[18];
  const float* out_W1     = (const float*)d_in[19];
  const float* out_b1     = (const float*)d_in[20];
  const float* out_W2     = (const float*)d_in[21];
  const float* out_b2     = (const float*)d_in[22];

  int NE   = in_sizes[0];
  int TOT  = in_sizes[3];
  int IN   = in_sizes[2] / TOT;
  int CH   = in_sizes[7];
  int COV  = in_sizes[6] / CH;
  int B    = in_sizes[4] / COV;
  int OUTD = in_sizes[22];
  int n_steps = out_size / (B * OUTD) - 1;
  int OPE  = TOT / NE;

  char* ws = (char*)d_ws;
  int* evtabT = (int*)ws;                       // [B][NEC], transposed
  size_t evbytes = (size_t)B * NEC * sizeof(int);
  size_t off1 = (evbytes + 255) & ~(size_t)255;
  unsigned* odeP = (unsigned*)(ws + off1);
  unsigned* bayP = odeP + 3 * 64 * 32;
  unsigned* wihP = bayP + 3 * 64 * 32;
  size_t off2 = off1 + (((3 * 64 * 32 * 2 + 3 * 64 * 4) * sizeof(unsigned) + 255) & ~(size_t)255);
  f16* w1P = (f16*)(ws + off2);
  size_t off3 = off2 + ((16 * 512 * sizeof(f16) + 255) & ~(size_t)255);
  f16* hp16 = (f16*)(ws + off3);

  hipMemsetAsync(evtabT, 0, evbytes, stream);
  build_evtab_kernel<<<NE, 256, 0, stream>>>(sample_ids, time_ptr, evtabT, B, OPE);
  pack_pairs_kernel<<<24, 256, 0, stream>>>(ghr_W, ghz_W, ghh_W, gb_Whh, gb_Wih,
                                            odeP, bayP, wihP, IN);
  pack_head_kernel<<<16, 64, 0, stream>>>(out_W1, w1P);
  evolve_kernel<<<B, 128, 0, stream>>>(
      time_uniq, X, covs, cov_W1, cov_b1, cov_W2, cov_b2,
      gb_bih, gb_bhh, gx_b, odeP, bayP, wihP,
      evtabT, hp16, B, NE, n_steps, IN, COV);
  long nrows = (long)(n_steps + 1) * B;
  int hb = (int)((nrows + 255) / 256);
  head_mfma_kernel<<<hb, 256, 0, stream>>>(hp16, w1P, out_b1, out_W2, out_b2,
                                           (float*)d_out, nrows);
}